// Round 3
// baseline (1118.330 us; speedup 1.0000x reference)
//
#include <hip/hip_runtime.h>
#include <hip/hip_bf16.h>
#include <math.h>

// Problem constants (B=4, S=2048 -> T=8192 tokens)
#define T_TOK 8192
#define DM    1024
#define NE    8
#define HD    4096

typedef __bf16 bf16;
typedef __attribute__((ext_vector_type(8))) __bf16 bf16x8;
typedef __attribute__((ext_vector_type(4))) __bf16 bf16x4;
typedef __attribute__((ext_vector_type(4))) float  f32x4;

__device__ __forceinline__ void gl_lds16(const void* g, void* l) {
  __builtin_amdgcn_global_load_lds((const __attribute__((address_space(1))) void*)g,
                                   (__attribute__((address_space(3))) void*)l, 16, 0, 0);
}

__device__ __forceinline__ int imin(int a, int b) { return a < b ? a : b; }

// ---------------- zero out + counts ----------------
__global__ void zero_kernel(float* __restrict__ out, int* __restrict__ counts) {
  size_t stride = (size_t)gridDim.x * blockDim.x;
  size_t n4 = (size_t)T_TOK * DM / 4;
  for (size_t i = (size_t)blockIdx.x * blockDim.x + threadIdx.x; i < n4; i += stride) {
    float4 z = {0.f, 0.f, 0.f, 0.f};
    ((float4*)out)[i] = z;
  }
  if (blockIdx.x == 0 && threadIdx.x < NE) counts[threadIdx.x] = 0;
}

// ---------------- x fp32 -> bf16 ----------------
__global__ void cvt_x_kernel(const float* __restrict__ x, bf16* __restrict__ xb) {
  size_t stride = (size_t)gridDim.x * blockDim.x;
  size_t n4 = (size_t)T_TOK * DM / 4;
  for (size_t i = (size_t)blockIdx.x * blockDim.x + threadIdx.x; i < n4; i += stride) {
    float4 v = ((const float4*)x)[i];
    bf16x4 o;
    o[0] = (bf16)v.x; o[1] = (bf16)v.y; o[2] = (bf16)v.z; o[3] = (bf16)v.w;
    *(bf16x4*)(xb + 4 * i) = o;
  }
}

// ---------------- transpose + cvt: in [e][R][C] fp32 -> out [e][C][R] bf16 ----------------
// 64x64 tile, vectorized bf16x8 stores (8 rows x 128B runs per wave).
__global__ void transpose_cvt_kernel(const float* __restrict__ in, bf16* __restrict__ out,
                                     int R, int C) {
  __shared__ float tile[64][65];
  int e = blockIdx.z;
  int c0 = blockIdx.x * 64, r0 = blockIdx.y * 64;
  int tid = threadIdx.x;
  int lr = tid >> 2, lc = (tid & 3) * 16;
  const float* src = in + ((size_t)e * R + r0 + lr) * C + c0 + lc;
#pragma unroll
  for (int q = 0; q < 4; ++q) {
    float4 v = *(const float4*)(src + q * 4);
    tile[lr][lc + q * 4 + 0] = v.x;
    tile[lr][lc + q * 4 + 1] = v.y;
    tile[lr][lc + q * 4 + 2] = v.z;
    tile[lr][lc + q * 4 + 3] = v.w;
  }
  __syncthreads();
  int oc = tid >> 3;      // 0..31
  int rchunk = tid & 7;   // 0..7
#pragma unroll
  for (int q = 0; q < 2; ++q) {
    int ocq = oc + q * 32;
    bf16x8 o;
#pragma unroll
    for (int k = 0; k < 8; ++k) o[k] = (bf16)tile[rchunk * 8 + k][ocq];
    *(bf16x8*)(out + ((size_t)e * C + c0 + ocq) * R + r0 + rchunk * 8) = o;
  }
}

// ---------------- gating: logits (double), softmax, top-2, compaction ----------------
__global__ void gating_kernel(const float* __restrict__ x, const float* __restrict__ Wg,
                              const float* __restrict__ bg, int* __restrict__ counts,
                              int* __restrict__ tokl, float* __restrict__ wgt) {
  int t = blockIdx.x * 4 + (threadIdx.x >> 6);
  int lane = threadIdx.x & 63;
  if (t >= T_TOK) return;
  double acc[NE];
#pragma unroll
  for (int e = 0; e < NE; ++e) acc[e] = 0.0;
  const float* xr = x + (size_t)t * DM;
  for (int d = lane; d < DM; d += 64) {
    float xv = xr[d];
#pragma unroll
    for (int e = 0; e < NE; ++e) acc[e] += (double)xv * (double)Wg[d * NE + e];
  }
#pragma unroll
  for (int e = 0; e < NE; ++e)
    for (int o = 32; o > 0; o >>= 1) acc[e] += __shfl_down(acc[e], o, 64);
  if (lane == 0) {
    float l[NE], w[NE];
    float m = -1e30f;
#pragma unroll
    for (int e = 0; e < NE; ++e) { l[e] = (float)acc[e] + bg[e]; m = fmaxf(m, l[e]); }
    float s = 0.f;
#pragma unroll
    for (int e = 0; e < NE; ++e) { w[e] = expf(l[e] - m); s += w[e]; }
    float inv = 1.f / s;
#pragma unroll
    for (int e = 0; e < NE; ++e) w[e] *= inv;
    int e1 = 0; float v1 = w[0];
#pragma unroll
    for (int e = 1; e < NE; ++e) if (w[e] > v1) { v1 = w[e]; e1 = e; }
    int e2 = -1; float v2 = -1.f;
#pragma unroll
    for (int e = 0; e < NE; ++e) if (e != e1 && w[e] > v2) { v2 = w[e]; e2 = e; }
    int s1 = atomicAdd(&counts[e1], 1);
    tokl[e1 * T_TOK + s1] = t; wgt[e1 * T_TOK + s1] = v1;
    int s2 = atomicAdd(&counts[e2], 1);
    tokl[e2 * T_TOK + s2] = t; wgt[e2 * T_TOK + s2] = v2;
  }
}

// ---------------- scan ----------------
__global__ void scan_kernel(const int* __restrict__ counts, int* __restrict__ offsets) {
  if (threadIdx.x == 0 && blockIdx.x == 0) {
    int s = 0;
#pragma unroll
    for (int e = 0; e < NE; ++e) { offsets[e] = s; s += counts[e]; }
    offsets[NE] = s;
  }
}

// ---------------- GEMM1: h = gelu(x[tok] @ W1[e] + b1[e]), bf16 out ----------------
// 128x256 block tile, 4 waves of 64x128. e = bid % NE -> expert pinned per XCD.
__global__ __launch_bounds__(256, 2) void gemm1_kernel(
    const bf16* __restrict__ xbf, const bf16* __restrict__ w1t,
    const float* __restrict__ b1, const int* __restrict__ counts,
    const int* __restrict__ offsets, const int* __restrict__ tokl,
    bf16* __restrict__ hbuf, int Hc, int cbase) {
  int bid = blockIdx.x;
  int e = bid % NE;
  int pe = bid / NE;
  int NT = Hc / 256;
  int nt = pe % NT, rt = pe / NT;
  int cnt = counts[e];
  if (rt * 128 >= cnt) return;
  __shared__ __align__(16) bf16 sA[128 * 32];
  __shared__ __align__(16) bf16 sB[256 * 32];
  int tid = threadIdx.x, lane = tid & 63, w = tid >> 6;
  // A staging: 2 x 1KB chunks per wave (rows w*32 .. w*32+31)
  int slotA = w * 2048 + lane * 16;
  int raw0 = slotA >> 6, ko = slotA & 63;
  int hoff = offsets[e];
  int r0 = imin(rt * 128 + raw0, cnt - 1);
  int r1 = imin(rt * 128 + raw0 + 16, cnt - 1);
  int t0 = tokl[e * T_TOK + r0];
  int t1 = tokl[e * T_TOK + r1];
  const char* ga0 = (const char*)(xbf + (size_t)t0 * DM) + ko;
  const char* ga1 = (const char*)(xbf + (size_t)t1 * DM) + ko;
  // B staging: 4 x 1KB chunks per wave (rows w*64 .. w*64+63)
  const char* gb[4];
#pragma unroll
  for (int c = 0; c < 4; ++c) {
    int rb = (w * 4096 + c * 1024 + lane * 16) >> 6;
    gb[c] = (const char*)(w1t + ((size_t)e * HD + cbase + nt * 256 + rb) * DM) + ko;
  }
  char* la = (char*)sA + w * 2048;
  char* lb = (char*)sB + w * 4096;
  f32x4 acc[4][8];
#pragma unroll
  for (int i = 0; i < 4; ++i)
#pragma unroll
    for (int j = 0; j < 8; ++j) acc[i][j] = {0.f, 0.f, 0.f, 0.f};
  int mw = (w & 1) * 64, nwv = (w >> 1) * 128;
  const bf16* pa = sA + (size_t)(mw + (lane & 15)) * 32 + (lane >> 4) * 8;
  const bf16* pb = sB + (size_t)(nwv + (lane & 15)) * 32 + (lane >> 4) * 8;
  for (int kk = 0; kk < DM; kk += 32) {
    gl_lds16(ga0 + kk * 2, la);
    gl_lds16(ga1 + kk * 2, la + 1024);
#pragma unroll
    for (int c = 0; c < 4; ++c) gl_lds16(gb[c] + kk * 2, lb + c * 1024);
    __syncthreads();
    bf16x8 af[4], bfr[8];
#pragma unroll
    for (int i = 0; i < 4; ++i) af[i] = *(const bf16x8*)(pa + i * 16 * 32);
#pragma unroll
    for (int j = 0; j < 8; ++j) bfr[j] = *(const bf16x8*)(pb + j * 16 * 32);
#pragma unroll
    for (int i = 0; i < 4; ++i)
#pragma unroll
      for (int j = 0; j < 8; ++j)
        acc[i][j] = __builtin_amdgcn_mfma_f32_16x16x32_bf16(af[i], bfr[j], acc[i][j], 0, 0, 0);
    __syncthreads();
  }
  int colq = lane & 15, rowq = (lane >> 4) * 4;
  float b1v[8];
#pragma unroll
  for (int j = 0; j < 8; ++j)
    b1v[j] = b1[(size_t)e * HD + cbase + nt * 256 + nwv + j * 16 + colq];
#pragma unroll
  for (int i = 0; i < 4; ++i) {
#pragma unroll
    for (int r = 0; r < 4; ++r) {
      int grow = rt * 128 + mw + i * 16 + rowq + r;
      if (grow < cnt) {
        size_t hrow = (size_t)(hoff + grow) * Hc;
#pragma unroll
        for (int j = 0; j < 8; ++j) {
          float v = acc[i][j][r] + b1v[j];
          float g = 0.5f * v * (1.f + erff(v * 0.70710678118654752f));
          hbuf[hrow + nt * 256 + nwv + j * 16 + colq] = (bf16)g;
        }
      }
    }
  }
}

// ---------------- GEMM2: out[tok] += w * (h @ W2[e] + b2[e]) ----------------
__global__ __launch_bounds__(256, 2) void gemm2_kernel(
    const bf16* __restrict__ hbuf, const bf16* __restrict__ w2t,
    const float* __restrict__ b2, const int* __restrict__ counts,
    const int* __restrict__ offsets, const int* __restrict__ tokl,
    const float* __restrict__ wgt, float* __restrict__ out,
    int Hc, int cbase, float b2scale) {
  int bid = blockIdx.x;
  int e = bid % NE;
  int pe = bid / NE;
  const int NT = DM / 256;
  int nt = pe % NT, rt = pe / NT;
  int cnt = counts[e];
  if (rt * 128 >= cnt) return;
  __shared__ __align__(16) bf16 sA[128 * 32];
  __shared__ __align__(16) bf16 sB[256 * 32];
  int tid = threadIdx.x, lane = tid & 63, w = tid >> 6;
  int slotA = w * 2048 + lane * 16;
  int raw0 = slotA >> 6, ko = slotA & 63;
  int hoff = offsets[e];
  int r0 = imin(rt * 128 + raw0, cnt - 1);
  int r1 = imin(rt * 128 + raw0 + 16, cnt - 1);
  const char* ga0 = (const char*)(hbuf + (size_t)(hoff + r0) * Hc) + ko;
  const char* ga1 = (const char*)(hbuf + (size_t)(hoff + r1) * Hc) + ko;
  const char* gb[4];
#pragma unroll
  for (int c = 0; c < 4; ++c) {
    int rb = (w * 4096 + c * 1024 + lane * 16) >> 6;
    gb[c] = (const char*)(w2t + ((size_t)e * DM + nt * 256 + rb) * HD + cbase) + ko;
  }
  char* la = (char*)sA + w * 2048;
  char* lb = (char*)sB + w * 4096;
  f32x4 acc[4][8];
#pragma unroll
  for (int i = 0; i < 4; ++i)
#pragma unroll
    for (int j = 0; j < 8; ++j) acc[i][j] = {0.f, 0.f, 0.f, 0.f};
  int mw = (w & 1) * 64, nwv = (w >> 1) * 128;
  const bf16* pa = sA + (size_t)(mw + (lane & 15)) * 32 + (lane >> 4) * 8;
  const bf16* pb = sB + (size_t)(nwv + (lane & 15)) * 32 + (lane >> 4) * 8;
  for (int kk = 0; kk < Hc; kk += 32) {
    gl_lds16(ga0 + kk * 2, la);
    gl_lds16(ga1 + kk * 2, la + 1024);
#pragma unroll
    for (int c = 0; c < 4; ++c) gl_lds16(gb[c] + kk * 2, lb + c * 1024);
    __syncthreads();
    bf16x8 af[4], bfr[8];
#pragma unroll
    for (int i = 0; i < 4; ++i) af[i] = *(const bf16x8*)(pa + i * 16 * 32);
#pragma unroll
    for (int j = 0; j < 8; ++j) bfr[j] = *(const bf16x8*)(pb + j * 16 * 32);
#pragma unroll
    for (int i = 0; i < 4; ++i)
#pragma unroll
      for (int j = 0; j < 8; ++j)
        acc[i][j] = __builtin_amdgcn_mfma_f32_16x16x32_bf16(af[i], bfr[j], acc[i][j], 0, 0, 0);
    __syncthreads();
  }
  int colq = lane & 15, rowq = (lane >> 4) * 4;
  float b2v[8];
#pragma unroll
  for (int j = 0; j < 8; ++j)
    b2v[j] = b2[(size_t)e * DM + nt * 256 + nwv + j * 16 + colq] * b2scale;
#pragma unroll
  for (int i = 0; i < 4; ++i) {
#pragma unroll
    for (int r = 0; r < 4; ++r) {
      int grow = rt * 128 + mw + i * 16 + rowq + r;
      if (grow < cnt) {
        float wv = wgt[e * T_TOK + grow];
        int tk = tokl[e * T_TOK + grow];
        float* orow = out + (size_t)tk * DM + nt * 256 + nwv;
#pragma unroll
        for (int j = 0; j < 8; ++j)
          atomicAdd(orow + j * 16 + colq, wv * (acc[i][j][r] + b2v[j]));
      }
    }
  }
}

extern "C" void kernel_launch(void* const* d_in, const int* in_sizes, int n_in,
                              void* d_out, int out_size, void* d_ws, size_t ws_size,
                              hipStream_t stream) {
  const float* x  = (const float*)d_in[0];
  const float* Wg = (const float*)d_in[1];
  const float* bg = (const float*)d_in[2];
  const float* W1 = (const float*)d_in[3];
  const float* b1 = (const float*)d_in[4];
  const float* W2 = (const float*)d_in[5];
  const float* b2 = (const float*)d_in[6];
  float* out = (float*)d_out;

  char* ws = (char*)d_ws;
  size_t off = 0;
  auto alloc = [&](size_t bytes) -> void* {
    void* p = ws + off;
    off = (off + bytes + 255) & ~(size_t)255;
    return p;
  };
  int*   counts  = (int*)alloc(NE * 4);
  int*   offsets = (int*)alloc((NE + 1) * 4);
  int*   tokl    = (int*)alloc((size_t)NE * T_TOK * 4);
  float* wgt     = (float*)alloc((size_t)NE * T_TOK * 4);
  bf16*  xbf     = (bf16*)alloc((size_t)T_TOK * DM * 2);
  bf16*  w1t     = (bf16*)alloc((size_t)NE * HD * DM * 2);
  bf16*  w2t     = (bf16*)alloc((size_t)NE * DM * HD * 2);
  size_t remain = ws_size > off ? ws_size - off : 0;
  int Hc = HD;
  while (Hc > 256 && (size_t)2 * T_TOK * Hc * 2 > remain) Hc >>= 1;  // h rows total = 2*T
  bf16* hbuf = (bf16*)alloc((size_t)2 * T_TOK * Hc * 2);

  zero_kernel<<<4096, 256, 0, stream>>>(out, counts);
  cvt_x_kernel<<<2048, 256, 0, stream>>>(x, xbf);
  transpose_cvt_kernel<<<dim3(HD / 64, DM / 64, NE), 256, 0, stream>>>(W1, w1t, DM, HD);
  transpose_cvt_kernel<<<dim3(DM / 64, HD / 64, NE), 256, 0, stream>>>(W2, w2t, HD, DM);
  gating_kernel<<<T_TOK / 4, 256, 0, stream>>>(x, Wg, bg, counts, tokl, wgt);
  scan_kernel<<<1, 64, 0, stream>>>(counts, offsets);

  int nchunk = HD / Hc;
  for (int c = 0; c < nchunk; ++c) {
    gemm1_kernel<<<NE * (Hc / 256) * (T_TOK / 128), 256, 0, stream>>>(
        xbf, w1t, b1, counts, offsets, tokl, hbuf, Hc, c * Hc);
    gemm2_kernel<<<NE * (DM / 256) * (T_TOK / 128), 256, 0, stream>>>(
        hbuf, w2t, b2, counts, offsets, tokl, wgt, out, Hc, c * Hc, c == 0 ? 1.f : 0.f);
  }
}

// Round 4
// 1008.087 us; speedup vs baseline: 1.1094x; 1.1094x over previous
//
#include <hip/hip_runtime.h>
#include <hip/hip_bf16.h>
#include <math.h>

// Problem constants (B=4, S=2048 -> T=8192 tokens)
#define T_TOK 8192
#define DM    1024
#define NE    8
#define HD    4096

typedef __bf16 bf16;
typedef __attribute__((ext_vector_type(8))) __bf16 bf16x8;
typedef __attribute__((ext_vector_type(4))) __bf16 bf16x4;
typedef __attribute__((ext_vector_type(4))) float  f32x4;

__device__ __forceinline__ void gl_lds16(const void* g, void* l) {
  __builtin_amdgcn_global_load_lds((const __attribute__((address_space(1))) void*)g,
                                   (__attribute__((address_space(3))) void*)l, 16, 0, 0);
}

// Raw barrier / waitcnt: keep prefetch loads in flight across the barrier
// (__syncthreads would force vmcnt(0) drain — the round-2/3 stall).
#define RAW_BARRIER() asm volatile("s_barrier" ::: "memory")
#define WAIT_VM4()    asm volatile("s_waitcnt vmcnt(4)" ::: "memory")

__device__ __forceinline__ int imin(int a, int b) { return a < b ? a : b; }

// ---------------- zero out + counts ----------------
__global__ void zero_kernel(float* __restrict__ out, int* __restrict__ counts) {
  size_t stride = (size_t)gridDim.x * blockDim.x;
  size_t n4 = (size_t)T_TOK * DM / 4;
  for (size_t i = (size_t)blockIdx.x * blockDim.x + threadIdx.x; i < n4; i += stride) {
    float4 z = {0.f, 0.f, 0.f, 0.f};
    ((float4*)out)[i] = z;
  }
  if (blockIdx.x == 0 && threadIdx.x < NE) counts[threadIdx.x] = 0;
}

// ---------------- x fp32 -> bf16 ----------------
__global__ void cvt_x_kernel(const float* __restrict__ x, bf16* __restrict__ xb) {
  size_t stride = (size_t)gridDim.x * blockDim.x;
  size_t n4 = (size_t)T_TOK * DM / 4;
  for (size_t i = (size_t)blockIdx.x * blockDim.x + threadIdx.x; i < n4; i += stride) {
    float4 v = ((const float4*)x)[i];
    bf16x4 o;
    o[0] = (bf16)v.x; o[1] = (bf16)v.y; o[2] = (bf16)v.z; o[3] = (bf16)v.w;
    *(bf16x4*)(xb + 4 * i) = o;
  }
}

// ---------------- transpose + cvt: in [e][R][C] fp32 -> out [e][C][R] bf16 ----------------
__global__ void transpose_cvt_kernel(const float* __restrict__ in, bf16* __restrict__ out,
                                     int R, int C) {
  __shared__ float tile[64][65];
  int e = blockIdx.z;
  int c0 = blockIdx.x * 64, r0 = blockIdx.y * 64;
  int tid = threadIdx.x;
  int lr = tid >> 2, lc = (tid & 3) * 16;
  const float* src = in + ((size_t)e * R + r0 + lr) * C + c0 + lc;
#pragma unroll
  for (int q = 0; q < 4; ++q) {
    float4 v = *(const float4*)(src + q * 4);
    tile[lr][lc + q * 4 + 0] = v.x;
    tile[lr][lc + q * 4 + 1] = v.y;
    tile[lr][lc + q * 4 + 2] = v.z;
    tile[lr][lc + q * 4 + 3] = v.w;
  }
  __syncthreads();
  int oc = tid >> 3;      // 0..31
  int rchunk = tid & 7;   // 0..7
#pragma unroll
  for (int q = 0; q < 2; ++q) {
    int ocq = oc + q * 32;
    bf16x8 o;
#pragma unroll
    for (int k = 0; k < 8; ++k) o[k] = (bf16)tile[rchunk * 8 + k][ocq];
    *(bf16x8*)(out + ((size_t)e * C + c0 + ocq) * R + r0 + rchunk * 8) = o;
  }
}

// ---------------- gating: logits (double), softmax, top-2, compaction ----------------
__global__ void gating_kernel(const float* __restrict__ x, const float* __restrict__ Wg,
                              const float* __restrict__ bg, int* __restrict__ counts,
                              int* __restrict__ tokl, float* __restrict__ wgt) {
  int t = blockIdx.x * 4 + (threadIdx.x >> 6);
  int lane = threadIdx.x & 63;
  if (t >= T_TOK) return;
  double acc[NE];
#pragma unroll
  for (int e = 0; e < NE; ++e) acc[e] = 0.0;
  const float* xr = x + (size_t)t * DM;
  for (int d = lane; d < DM; d += 64) {
    float xv = xr[d];
#pragma unroll
    for (int e = 0; e < NE; ++e) acc[e] += (double)xv * (double)Wg[d * NE + e];
  }
#pragma unroll
  for (int e = 0; e < NE; ++e)
    for (int o = 32; o > 0; o >>= 1) acc[e] += __shfl_down(acc[e], o, 64);
  if (lane == 0) {
    float l[NE], w[NE];
    float m = -1e30f;
#pragma unroll
    for (int e = 0; e < NE; ++e) { l[e] = (float)acc[e] + bg[e]; m = fmaxf(m, l[e]); }
    float s = 0.f;
#pragma unroll
    for (int e = 0; e < NE; ++e) { w[e] = expf(l[e] - m); s += w[e]; }
    float inv = 1.f / s;
#pragma unroll
    for (int e = 0; e < NE; ++e) w[e] *= inv;
    int e1 = 0; float v1 = w[0];
#pragma unroll
    for (int e = 1; e < NE; ++e) if (w[e] > v1) { v1 = w[e]; e1 = e; }
    int e2 = -1; float v2 = -1.f;
#pragma unroll
    for (int e = 0; e < NE; ++e) if (e != e1 && w[e] > v2) { v2 = w[e]; e2 = e; }
    int s1 = atomicAdd(&counts[e1], 1);
    tokl[e1 * T_TOK + s1] = t; wgt[e1 * T_TOK + s1] = v1;
    int s2 = atomicAdd(&counts[e2], 1);
    tokl[e2 * T_TOK + s2] = t; wgt[e2 * T_TOK + s2] = v2;
  }
}

// ---------------- scan ----------------
__global__ void scan_kernel(const int* __restrict__ counts, int* __restrict__ offsets) {
  if (threadIdx.x == 0 && blockIdx.x == 0) {
    int s = 0;
#pragma unroll
    for (int e = 0; e < NE; ++e) { offsets[e] = s; s += counts[e]; }
    offsets[NE] = s;
  }
}

// ---------------- GEMM1: h = gelu(x[tok] @ W1[e] + b1[e]), bf16 out ----------------
// 128x128 tile, BK=32, LDS double-buffer + raw-barrier pipeline. e = bid % NE.
__global__ __launch_bounds__(256, 3) void gemm1_kernel(
    const bf16* __restrict__ xbf, const bf16* __restrict__ w1t,
    const float* __restrict__ b1, const int* __restrict__ counts,
    const int* __restrict__ offsets, const int* __restrict__ tokl,
    bf16* __restrict__ hbuf, int Hc, int cbase) {
  int bid = blockIdx.x;
  int e = bid % NE;
  int pe = bid / NE;
  int NT = Hc / 128;
  int nt = pe % NT, rt = pe / NT;
  int cnt = counts[e];
  if (rt * 128 >= cnt) return;
  __shared__ __align__(16) bf16 sA[2][128 * 32];
  __shared__ __align__(16) bf16 sB[2][128 * 32];
  int tid = threadIdx.x, lane = tid & 63, w = tid >> 6;
  int slot = w * 2048 + lane * 16;            // byte slot in 8KB tile
  int ra0 = slot >> 6, ko = slot & 63;        // row (64B rows), byte-in-row
  int hoff = offsets[e];
  int r0 = imin(rt * 128 + ra0, cnt - 1);
  int r1 = imin(rt * 128 + ra0 + 16, cnt - 1);
  int t0 = tokl[e * T_TOK + r0];
  int t1 = tokl[e * T_TOK + r1];
  const char* ga0 = (const char*)(xbf + (size_t)t0 * DM) + ko;
  const char* ga1 = (const char*)(xbf + (size_t)t1 * DM) + ko;
  const char* gb0 = (const char*)(w1t + ((size_t)e * HD + cbase + nt * 128 + ra0) * DM) + ko;
  const char* gb1 = (const char*)(w1t + ((size_t)e * HD + cbase + nt * 128 + ra0 + 16) * DM) + ko;
  char* lab = (char*)sA + w * 2048;
  char* lbb = (char*)sB + w * 2048;
  f32x4 acc[4][4];
#pragma unroll
  for (int i = 0; i < 4; ++i)
#pragma unroll
    for (int j = 0; j < 4; ++j) acc[i][j] = {0.f, 0.f, 0.f, 0.f};
  int mw = (w & 1) * 64, nw = (w >> 1) * 64;
  const bf16* pa = &sA[0][0] + (size_t)(mw + (lane & 15)) * 32 + (lane >> 4) * 8;
  const bf16* pb = &sB[0][0] + (size_t)(nw + (lane & 15)) * 32 + (lane >> 4) * 8;
  const int K = DM / 32;
  // prologue: stage k=0 into buf 0
  gl_lds16(ga0, lab);
  gl_lds16(ga1, lab + 1024);
  gl_lds16(gb0, lbb);
  gl_lds16(gb1, lbb + 1024);
  for (int k = 0; k < K; ++k) {
    int nb = (k + 1) & 1;
    int kb = (k + 1 < K) ? (k + 1) * 64 : 0;  // byte offset; last iter: dummy refetch of k=0
    gl_lds16(ga0 + kb, lab + nb * 8192);
    gl_lds16(ga1 + kb, lab + nb * 8192 + 1024);
    gl_lds16(gb0 + kb, lbb + nb * 8192);
    gl_lds16(gb1 + kb, lbb + nb * 8192 + 1024);
    WAIT_VM4();      // own 4 loads of iter k landed
    RAW_BARRIER();   // everyone's landed
    int cb = (k & 1) * 4096;  // element offset into current buffer
    bf16x8 af[4], bfr[4];
#pragma unroll
    for (int i = 0; i < 4; ++i) af[i] = *(const bf16x8*)(pa + cb + i * 16 * 32);
#pragma unroll
    for (int j = 0; j < 4; ++j) bfr[j] = *(const bf16x8*)(pb + cb + j * 16 * 32);
#pragma unroll
    for (int i = 0; i < 4; ++i)
#pragma unroll
      for (int j = 0; j < 4; ++j)
        acc[i][j] = __builtin_amdgcn_mfma_f32_16x16x32_bf16(af[i], bfr[j], acc[i][j], 0, 0, 0);
    RAW_BARRIER();   // all reads of current buffer done before next overwrite
  }
  int colq = lane & 15, rowq = (lane >> 4) * 4;
  float b1v[4];
#pragma unroll
  for (int j = 0; j < 4; ++j)
    b1v[j] = b1[(size_t)e * HD + cbase + nt * 128 + nw + j * 16 + colq];
#pragma unroll
  for (int i = 0; i < 4; ++i) {
#pragma unroll
    for (int r = 0; r < 4; ++r) {
      int grow = rt * 128 + mw + i * 16 + rowq + r;
      if (grow < cnt) {
        size_t hrow = (size_t)(hoff + grow) * Hc;
#pragma unroll
        for (int j = 0; j < 4; ++j) {
          float v = acc[i][j][r] + b1v[j];
          float g = 0.5f * v * (1.f + erff(v * 0.70710678118654752f));
          hbuf[hrow + nt * 128 + nw + j * 16 + colq] = (bf16)g;
        }
      }
    }
  }
}

// ---------------- GEMM2: out[tok] += w * (h @ W2[e] + b2[e]) ----------------
__global__ __launch_bounds__(256, 3) void gemm2_kernel(
    const bf16* __restrict__ hbuf, const bf16* __restrict__ w2t,
    const float* __restrict__ b2, const int* __restrict__ counts,
    const int* __restrict__ offsets, const int* __restrict__ tokl,
    const float* __restrict__ wgt, float* __restrict__ out,
    int Hc, int cbase, float b2scale) {
  int bid = blockIdx.x;
  int e = bid % NE;
  int pe = bid / NE;
  const int NT = DM / 128;
  int nt = pe % NT, rt = pe / NT;
  int cnt = counts[e];
  if (rt * 128 >= cnt) return;
  __shared__ __align__(16) bf16 sA[2][128 * 32];
  __shared__ __align__(16) bf16 sB[2][128 * 32];
  int tid = threadIdx.x, lane = tid & 63, w = tid >> 6;
  int slot = w * 2048 + lane * 16;
  int ra0 = slot >> 6, ko = slot & 63;
  int hoff = offsets[e];
  int r0 = imin(rt * 128 + ra0, cnt - 1);
  int r1 = imin(rt * 128 + ra0 + 16, cnt - 1);
  const char* ga0 = (const char*)(hbuf + (size_t)(hoff + r0) * Hc) + ko;
  const char* ga1 = (const char*)(hbuf + (size_t)(hoff + r1) * Hc) + ko;
  const char* gb0 = (const char*)(w2t + ((size_t)e * DM + nt * 128 + ra0) * HD + cbase) + ko;
  const char* gb1 = (const char*)(w2t + ((size_t)e * DM + nt * 128 + ra0 + 16) * HD + cbase) + ko;
  char* lab = (char*)sA + w * 2048;
  char* lbb = (char*)sB + w * 2048;
  f32x4 acc[4][4];
#pragma unroll
  for (int i = 0; i < 4; ++i)
#pragma unroll
    for (int j = 0; j < 4; ++j) acc[i][j] = {0.f, 0.f, 0.f, 0.f};
  int mw = (w & 1) * 64, nw = (w >> 1) * 64;
  const bf16* pa = &sA[0][0] + (size_t)(mw + (lane & 15)) * 32 + (lane >> 4) * 8;
  const bf16* pb = &sB[0][0] + (size_t)(nw + (lane & 15)) * 32 + (lane >> 4) * 8;
  const int K = Hc / 32;
  gl_lds16(ga0, lab);
  gl_lds16(ga1, lab + 1024);
  gl_lds16(gb0, lbb);
  gl_lds16(gb1, lbb + 1024);
  for (int k = 0; k < K; ++k) {
    int nb = (k + 1) & 1;
    int kb = (k + 1 < K) ? (k + 1) * 64 : 0;
    gl_lds16(ga0 + kb, lab + nb * 8192);
    gl_lds16(ga1 + kb, lab + nb * 8192 + 1024);
    gl_lds16(gb0 + kb, lbb + nb * 8192);
    gl_lds16(gb1 + kb, lbb + nb * 8192 + 1024);
    WAIT_VM4();
    RAW_BARRIER();
    int cb = (k & 1) * 4096;
    bf16x8 af[4], bfr[4];
#pragma unroll
    for (int i = 0; i < 4; ++i) af[i] = *(const bf16x8*)(pa + cb + i * 16 * 32);
#pragma unroll
    for (int j = 0; j < 4; ++j) bfr[j] = *(const bf16x8*)(pb + cb + j * 16 * 32);
#pragma unroll
    for (int i = 0; i < 4; ++i)
#pragma unroll
      for (int j = 0; j < 4; ++j)
        acc[i][j] = __builtin_amdgcn_mfma_f32_16x16x32_bf16(af[i], bfr[j], acc[i][j], 0, 0, 0);
    RAW_BARRIER();
  }
  int colq = lane & 15, rowq = (lane >> 4) * 4;
  float b2v[4];
#pragma unroll
  for (int j = 0; j < 4; ++j)
    b2v[j] = b2[(size_t)e * DM + nt * 128 + nw + j * 16 + colq] * b2scale;
#pragma unroll
  for (int i = 0; i < 4; ++i) {
#pragma unroll
    for (int r = 0; r < 4; ++r) {
      int grow = rt * 128 + mw + i * 16 + rowq + r;
      if (grow < cnt) {
        float wv = wgt[e * T_TOK + grow];
        int tk = tokl[e * T_TOK + grow];
        float* orow = out + (size_t)tk * DM + nt * 128 + nw;
#pragma unroll
        for (int j = 0; j < 4; ++j)
          atomicAdd(orow + j * 16 + colq, wv * (acc[i][j][r] + b2v[j]));
      }
    }
  }
}

extern "C" void kernel_launch(void* const* d_in, const int* in_sizes, int n_in,
                              void* d_out, int out_size, void* d_ws, size_t ws_size,
                              hipStream_t stream) {
  const float* x  = (const float*)d_in[0];
  const float* Wg = (const float*)d_in[1];
  const float* bg = (const float*)d_in[2];
  const float* W1 = (const float*)d_in[3];
  const float* b1 = (const float*)d_in[4];
  const float* W2 = (const float*)d_in[5];
  const float* b2 = (const float*)d_in[6];
  float* out = (float*)d_out;

  char* ws = (char*)d_ws;
  size_t off = 0;
  auto alloc = [&](size_t bytes) -> void* {
    void* p = ws + off;
    off = (off + bytes + 255) & ~(size_t)255;
    return p;
  };
  int*   counts  = (int*)alloc(NE * 4);
  int*   offsets = (int*)alloc((NE + 1) * 4);
  int*   tokl    = (int*)alloc((size_t)NE * T_TOK * 4);
  float* wgt     = (float*)alloc((size_t)NE * T_TOK * 4);
  bf16*  xbf     = (bf16*)alloc((size_t)T_TOK * DM * 2);
  bf16*  w1t     = (bf16*)alloc((size_t)NE * HD * DM * 2);
  bf16*  w2t     = (bf16*)alloc((size_t)NE * DM * HD * 2);
  size_t remain = ws_size > off ? ws_size - off : 0;
  int Hc = HD;
  while (Hc > 128 && (size_t)2 * T_TOK * Hc * 2 > remain) Hc >>= 1;  // h rows total = 2*T
  bf16* hbuf = (bf16*)alloc((size_t)2 * T_TOK * Hc * 2);

  zero_kernel<<<4096, 256, 0, stream>>>(out, counts);
  cvt_x_kernel<<<2048, 256, 0, stream>>>(x, xbf);
  transpose_cvt_kernel<<<dim3(HD / 64, DM / 64, NE), 256, 0, stream>>>(W1, w1t, DM, HD);
  transpose_cvt_kernel<<<dim3(DM / 64, HD / 64, NE), 256, 0, stream>>>(W2, w2t, HD, DM);
  gating_kernel<<<T_TOK / 4, 256, 0, stream>>>(x, Wg, bg, counts, tokl, wgt);
  scan_kernel<<<1, 64, 0, stream>>>(counts, offsets);

  int nchunk = HD / Hc;
  for (int c = 0; c < nchunk; ++c) {
    gemm1_kernel<<<NE * (Hc / 128) * (T_TOK / 128), 256, 0, stream>>>(
        xbf, w1t, b1, counts, offsets, tokl, hbuf, Hc, c * Hc);
    gemm2_kernel<<<NE * (DM / 128) * (T_TOK / 128), 256, 0, stream>>>(
        hbuf, w2t, b2, counts, offsets, tokl, wgt, out, Hc, c * Hc, c == 0 ? 1.f : 0.f);
  }
}